// Round 1
// baseline (104.159 us; speedup 1.0000x reference)
//
#include <hip/hip_runtime.h>

// x: [1, 2049, 8192] f32 ; lambda: [1, 8192] f32
// out: [1, 1+2048+8192, 8192] f32
//   row 0           : center = lam*x0 - 0.5*lam*lower
//   rows 1..2048    : x[e]*lam
//   rows 2049..10240: extra[r][n] = (rows[n]==r) ? -0.5*lam*lower : 0

// K1: fused errs-scale + per-row-chunk abs partial sums.
// grid (N/1024, PBY), block 256, each thread owns 4 contiguous columns.
__global__ __launch_bounds__(256) void k_errs_partial(
    const float* __restrict__ x, const float* __restrict__ lam,
    float* __restrict__ out, float* __restrict__ partials,
    int N, int rowsPerBlock)
{
    const int col = (blockIdx.x * 256 + threadIdx.x) * 4;
    const int r0  = 1 + blockIdx.y * rowsPerBlock;
    const float4 l4 = *(const float4*)(lam + col);
    float ax = 0.f, ay = 0.f, az = 0.f, aw = 0.f;
    #pragma unroll 4
    for (int r = r0; r < r0 + rowsPerBlock; ++r) {
        const float4 v = *(const float4*)(x + (size_t)r * N + col);
        ax += fabsf(v.x); ay += fabsf(v.y); az += fabsf(v.z); aw += fabsf(v.w);
        float4 o;
        o.x = v.x * l4.x; o.y = v.y * l4.y; o.z = v.z * l4.z; o.w = v.w * l4.w;
        *(float4*)(out + (size_t)r * N + col) = o;
    }
    float4 a; a.x = ax; a.y = ay; a.z = az; a.w = aw;
    *(float4*)(partials + (size_t)blockIdx.y * N + col) = a;
}

// K2: reduce partials per column, write center (out row 0), flags, vals.
__global__ __launch_bounds__(256) void k_stats(
    const float* __restrict__ x, const float* __restrict__ lam,
    const float* __restrict__ partials,
    float* __restrict__ out, float* __restrict__ vals, int* __restrict__ flags,
    int N, int P)
{
    const int n = blockIdx.x * 256 + threadIdx.x;
    float s = 0.f;
    for (int p = 0; p < P; ++p) s += partials[(size_t)p * N + n];
    const float x0 = x[n];          // row 0 of x
    const float l  = lam[n];
    const float lower = x0 - s;
    const float upper = x0 + s;
    out[n] = l * x0 - l * lower * 0.5f;          // center
    const bool has = (lower < 0.f) && (upper > 0.f);
    flags[n] = has ? 1 : 0;
    vals[n]  = has ? (-l * lower * 0.5f) : 0.f;
}

// K3: single-block prefix scan of flags -> compacted row index (or -1).
__global__ __launch_bounds__(1024) void k_scan(
    const int* __restrict__ flags, int* __restrict__ rowsArr, int N)
{
    __shared__ int sh[1024];
    const int t = threadIdx.x;
    const int per = N / 1024;
    const int base = t * per;
    int cnt = 0;
    for (int i = 0; i < per; ++i) cnt += flags[base + i];
    sh[t] = cnt;
    __syncthreads();
    // Hillis-Steele inclusive scan over 1024 thread sums
    for (int off = 1; off < 1024; off <<= 1) {
        const int mine = sh[t];
        const int add = (t >= off) ? sh[t - off] : 0;
        __syncthreads();
        sh[t] = mine + add;
        __syncthreads();
    }
    int run = (t > 0) ? sh[t - 1] : 0;   // exclusive prefix
    for (int i = 0; i < per; ++i) {
        const int n = base + i;
        if (flags[n]) { rowsArr[n] = run; run += 1; }
        else          { rowsArr[n] = -1; }
    }
}

// K4: write the N x N extra block: (rows[n]==r) ? vals[n] : 0.
// grid (N/1024, N/rowsPerBlock), block 256, 4 cols/thread; rows/vals stay in regs.
__global__ __launch_bounds__(256) void k_extra(
    const float* __restrict__ vals, const int* __restrict__ rowsArr,
    float* __restrict__ outExtra, int N, int rowsPerBlock)
{
    const int col = (blockIdx.x * 256 + threadIdx.x) * 4;
    const int r0  = blockIdx.y * rowsPerBlock;
    const int4   rw = *(const int4*)(rowsArr + col);
    const float4 vv = *(const float4*)(vals + col);
    for (int r = r0; r < r0 + rowsPerBlock; ++r) {
        float4 o;
        o.x = (rw.x == r) ? vv.x : 0.f;
        o.y = (rw.y == r) ? vv.y : 0.f;
        o.z = (rw.z == r) ? vv.z : 0.f;
        o.w = (rw.w == r) ? vv.w : 0.f;
        *(float4*)(outExtra + (size_t)r * N + col) = o;
    }
}

extern "C" void kernel_launch(void* const* d_in, const int* in_sizes, int n_in,
                              void* d_out, int out_size, void* d_ws, size_t ws_size,
                              hipStream_t stream) {
    const float* x   = (const float*)d_in[0];
    const float* lam = (const float*)d_in[1];
    float* out = (float*)d_out;

    const int N  = in_sizes[1];            // 8192
    const int E1 = in_sizes[0] / N;        // 2049
    const int E  = E1 - 1;                 // 2048

    const int PBY = 32;                    // partial-sum row chunks
    float* partials = (float*)d_ws;                     // [PBY][N]
    float* vals     = partials + (size_t)PBY * N;       // [N]
    int*   flags    = (int*)(vals + N);                 // [N]
    int*   rowsArr  = flags + N;                        // [N]

    dim3 blk(256);

    dim3 g1(N / 1024, PBY);
    hipLaunchKernelGGL(k_errs_partial, g1, blk, 0, stream,
                       x, lam, out, partials, N, E / PBY);

    hipLaunchKernelGGL(k_stats, dim3(N / 256), blk, 0, stream,
                       x, lam, partials, out, vals, flags, N, PBY);

    hipLaunchKernelGGL(k_scan, dim3(1), dim3(1024), 0, stream,
                       flags, rowsArr, N);

    dim3 g3(N / 1024, N / 64);
    hipLaunchKernelGGL(k_extra, g3, blk, 0, stream,
                       vals, rowsArr, out + (size_t)E1 * N, N, 64);
}